// Round 1
// 72.345 us; speedup vs baseline: 1.0186x; 1.0186x over previous
//
#include <hip/hip_runtime.h>

// TransientCombNoise: B=32, T=2000, BLOCK=64 -> N = 64000 rows x 64 samples.
//
// Math collapse (verified in prior rounds): delay in [33,63] => comb depth <= 1:
//   y[s] = x[s] + tilt * (s >= delay ? x[s-delay] : 0)
//   x[s] = noise[s] * exp2(s*c) * energy,  c = -log2(e)/attack
// R3 collapse: factor the envelope through the delay tap:
//   y[s] = exp2(s*c) * energy * ( noise[s] + g * noise[s-delay] ),
//   g = tilt * exp2(-delay*c)   (row-uniform).
// => the delayed tap is a RAW-noise reload from the same 256B row (L1 hit),
//    killing all 4 comb ds_bpermute + the 4-way element-select chain.
//
// Layout unchanged from R2: 16 lanes/row (float4 each), 4 rows/wave,
// 4 waves/block -> 16 rows/block, 4000 blocks.

#define NROWS 64000

__global__ __launch_bounds__(256) void TransientCombNoise_kernel(
    const float4* __restrict__ params,   // [NROWS] float4
    const float*  __restrict__ noise,    // [NROWS*64] floats
    float4* __restrict__ out4)           // [NROWS*16] float4
{
    const int lane      = threadIdx.x & 63;
    const int waveInBlk = threadIdx.x >> 6;        // 0..3
    const int rowInWave = lane >> 4;               // 0..3
    const int chunk     = lane & 15;               // 0..15 -> samples 4c..4c+3
    const int row       = (blockIdx.x * 4 + waveInBlk) * 4 + rowInWave;

    // Per-row params (16 lanes share one 16B line; wave touches one cacheline)
    const float4 p = params[row];
    const float attack = fmaxf((0.0005f + p.x * 0.0495f) * 16000.0f, 1.0f);
    const float c      = -1.44269504088896f / attack;   // exp(-s/a) = exp2(s*c)
    const float energy = p.y;
    const float tilt   = p.z * 2.0f - 1.0f;
    const float bw     = 0.05f + p.w * 0.95f;
    int delay = (int)(64.0f * (0.5f + 0.5f * bw));      // trunc, in [33,63]
    delay = max(1, min(delay, 480));

    // Envelope folded through the delay: tilt * exp2(-delay*c).
    // Max exponent ~ 63*1.4427/8 ~ 11.4 -> no overflow; product with env_s
    // cancels back to <= |tilt| for valid taps.
    const float g = tilt * exp2f((float)(-delay) * c);

    const float* nrow = noise + row * 64;
    const int s0 = chunk << 2;

    // Current samples: one coalesced 16B load
    const float4 nz = ((const float4*)nrow)[chunk];

    // Delayed raw-noise taps: same row, t = s - delay (clamped load + mask).
    // These hit L1 (row's 256B was just fetched by this wave).
    const int t0 = s0 - delay;
    float nd0 = nrow[max(t0 + 0, 0)];
    float nd1 = nrow[max(t0 + 1, 0)];
    float nd2 = nrow[max(t0 + 2, 0)];
    float nd3 = nrow[max(t0 + 3, 0)];
    nd0 = (t0 + 0 >= 0) ? nd0 : 0.0f;
    nd1 = (t0 + 1 >= 0) ? nd1 : 0.0f;
    nd2 = (t0 + 2 >= 0) ? nd2 : 0.0f;
    nd3 = (t0 + 3 >= 0) ? nd3 : 0.0f;

    // Envelope: 1 exp2 for the base + incremental ratio (saves 2 transcendentals)
    const float r  = exp2f(c);
    const float e0 = exp2f((float)s0 * c) * energy;
    const float e1 = e0 * r;
    const float e2 = e1 * r;
    const float e3 = e2 * r;

    const float y0 = e0 * (nz.x + g * nd0);
    const float y1 = e1 * (nz.y + g * nd1);
    const float y2 = e2 * (nz.z + g * nd2);
    const float y3 = e3 * (nz.w + g * nd3);

    // Sum of y^2 across the 16 lanes of this row (xor masks 1,2,4,8 stay in-group)
    float ss = y0*y0 + y1*y1 + y2*y2 + y3*y3;
    #pragma unroll
    for (int off = 1; off < 16; off <<= 1)
        ss += __shfl_xor(ss, off, 64);

    const float inv = 1.0f / sqrtf(ss * (1.0f / 64.0f) + 1e-5f);
    out4[row * 16 + chunk] = make_float4(y0*inv, y1*inv, y2*inv, y3*inv);
}

extern "C" void kernel_launch(void* const* d_in, const int* in_sizes, int n_in,
                              void* d_out, int out_size, void* d_ws, size_t ws_size,
                              hipStream_t stream) {
    const float4* params = (const float4*)d_in[0];  // [64000,4]
    const float*  noise  = (const float*)d_in[1];   // [64000,64]
    float4* out          = (float4*)d_out;          // [64000,64] as float4

    // 16 rows per 256-thread block -> 4000 blocks
    TransientCombNoise_kernel<<<dim3(NROWS / 16), dim3(256), 0, stream>>>(params, noise, out);
}